// Round 5
// baseline (103.165 us; speedup 1.0000x reference)
//
#include <hip/hip_runtime.h>

// hnode_prompt_layer_feature_cat_edge
// out[d, 0:128]   = (sum_{e: dst[e]=d} emb[src[e]]) * w
// out[d, 128:160] =  sum_{e: dst[e]=d} e_feat[e]
//
// R5 = R4 (bucket CSR + MLP gather: emb unroll 4, e_feat 4-edges/iter across
// all 32 lanes) with the shfl-under-divergence bug fixed:
// ds_bpermute (__shfl) reads from exec-INACTIVE source lanes are UNDEFINED,
// so every __shfl must execute convergently within the 32-lane node group.
// The e_feat tail now hoists the shfl (clamped src index) out of the guard.

#define D_FT 128
#define D_E 32
#define D_OUT (D_FT + D_E)
#define CAP 32

__global__ void place_bucket_kernel(const int* __restrict__ src_idx,
                                    const int* __restrict__ dst_idx,
                                    int* __restrict__ cursor,
                                    int2* __restrict__ bucket,
                                    int* __restrict__ ovf,
                                    int* __restrict__ ovf_cnt, int E) {
    int i = blockIdx.x * blockDim.x + threadIdx.x;
    if (i >= E) return;
    int d = dst_idx[i];
    int slot = atomicAdd(&cursor[d], 1);
    if (slot < CAP) {
        int2 pr; pr.x = src_idx[i]; pr.y = i;
        bucket[(size_t)d * CAP + slot] = pr;
    } else {
        int p = atomicAdd(ovf_cnt, 1);
        ovf[p] = i;
    }
}

__global__ void gather_bucket_kernel(const float* __restrict__ emb,
                                     const float* __restrict__ e_feat,
                                     const float* __restrict__ w,
                                     const int* __restrict__ cursor,
                                     const int2* __restrict__ bucket,
                                     float* __restrict__ out, int N) {
    int g = (blockIdx.x * blockDim.x + threadIdx.x) >> 5;   // node
    if (g >= N) return;
    const int q  = threadIdx.x & 31;
    const int qg = q >> 3;        // e_feat edge-group 0..3
    const int ql = q & 7;         // float4 slot within e_feat row
    int cnt = cursor[g];
    cnt = cnt > CAP ? CAP : cnt;
    int2 pr = make_int2(0, 0);
    if (q < cnt) pr = bucket[(size_t)g * CAP + q];

    float4 accft = make_float4(0.f, 0.f, 0.f, 0.f);
    float4 acce  = make_float4(0.f, 0.f, 0.f, 0.f);  // per-lane partial (group qg)

    int i = 0;
    for (; i + 4 <= cnt; i += 4) {
        // all shfls here are convergent: loop condition is uniform per group,
        // source lanes i..i+3 < cnt are active and hold valid pr.
        int s0 = __shfl(pr.x, i + 0, 32);
        int s1 = __shfl(pr.x, i + 1, 32);
        int s2 = __shfl(pr.x, i + 2, 32);
        int s3 = __shfl(pr.x, i + 3, 32);
        int ee = __shfl(pr.y, i + qg, 32);
        float4 v0 = *reinterpret_cast<const float4*>(emb + (size_t)s0 * D_FT + q * 4);
        float4 v1 = *reinterpret_cast<const float4*>(emb + (size_t)s1 * D_FT + q * 4);
        float4 v2 = *reinterpret_cast<const float4*>(emb + (size_t)s2 * D_FT + q * 4);
        float4 v3 = *reinterpret_cast<const float4*>(emb + (size_t)s3 * D_FT + q * 4);
        float4 a  = *reinterpret_cast<const float4*>(e_feat + (size_t)ee * D_E + ql * 4);
        accft.x += (v0.x + v1.x) + (v2.x + v3.x);
        accft.y += (v0.y + v1.y) + (v2.y + v3.y);
        accft.z += (v0.z + v1.z) + (v2.z + v3.z);
        accft.w += (v0.w + v1.w) + (v2.w + v3.w);
        acce.x += a.x; acce.y += a.y; acce.z += a.z; acce.w += a.w;
    }
    // e_feat tail (r = cnt - i in [0,3]): shfl OUTSIDE the divergent guard,
    // clamped source index -> executed by all 32 lanes, sources active.
    {
        int t = i + qg;
        int tsrc = (t < cnt) ? t : 0;
        int ee = __shfl(pr.y, tsrc, 32);
        if (t < cnt) {
            float4 a = *reinterpret_cast<const float4*>(e_feat + (size_t)ee * D_E + ql * 4);
            acce.x += a.x; acce.y += a.y; acce.z += a.z; acce.w += a.w;
        }
    }
    // emb tail: j and cnt uniform per group -> convergent shfl.
    for (int j = i; j < cnt; ++j) {
        int s = __shfl(pr.x, j, 32);
        float4 v = *reinterpret_cast<const float4*>(emb + (size_t)s * D_FT + q * 4);
        accft.x += v.x; accft.y += v.y; accft.z += v.z; accft.w += v.w;
    }

    // reduce acce across the 4 edge-groups: lanes q<8 end with the total
    acce.x += __shfl_xor(acce.x, 8, 32);
    acce.y += __shfl_xor(acce.y, 8, 32);
    acce.z += __shfl_xor(acce.z, 8, 32);
    acce.w += __shfl_xor(acce.w, 8, 32);
    acce.x += __shfl_xor(acce.x, 16, 32);
    acce.y += __shfl_xor(acce.y, 16, 32);
    acce.z += __shfl_xor(acce.z, 16, 32);
    acce.w += __shfl_xor(acce.w, 16, 32);

    float4 wv = *reinterpret_cast<const float4*>(w + q * 4);
    float* o = out + (size_t)g * D_OUT;
    *reinterpret_cast<float4*>(o + q * 4) =
        make_float4(accft.x * wv.x, accft.y * wv.y, accft.z * wv.z, accft.w * wv.w);
    if (q < 8)
        *reinterpret_cast<float4*>(o + D_FT + q * 4) = acce;
}

// Drain overflow edges (deg > CAP; ~never fires for this data, correct always).
__global__ void ovf_scatter_kernel(const float* __restrict__ emb,
                                   const float* __restrict__ e_feat,
                                   const float* __restrict__ w,
                                   const int* __restrict__ src_idx,
                                   const int* __restrict__ dst_idx,
                                   const int* __restrict__ ovf,
                                   const int* __restrict__ ovf_cnt,
                                   float* __restrict__ out) {
    int n = *ovf_cnt;
    int total = n * 40;   // 32 ft float4-slots + 8 e float4-slots per edge
    for (int t = blockIdx.x * blockDim.x + threadIdx.x; t < total;
         t += gridDim.x * blockDim.x) {
        int e = t / 40, slot = t % 40;
        int eid = ovf[e];
        int d = dst_idx[eid];
        float* o = out + (size_t)d * D_OUT;
        if (slot < 32) {
            int s = src_idx[eid];
            float4 v  = *reinterpret_cast<const float4*>(emb + (size_t)s * D_FT + slot * 4);
            float4 wv = *reinterpret_cast<const float4*>(w + slot * 4);
            atomicAdd(o + slot * 4 + 0, v.x * wv.x);
            atomicAdd(o + slot * 4 + 1, v.y * wv.y);
            atomicAdd(o + slot * 4 + 2, v.z * wv.z);
            atomicAdd(o + slot * 4 + 3, v.w * wv.w);
        } else {
            int qq = slot - 32;
            float4 ve = *reinterpret_cast<const float4*>(e_feat + (size_t)eid * D_E + qq * 4);
            atomicAdd(o + D_FT + qq * 4 + 0, ve.x);
            atomicAdd(o + D_FT + qq * 4 + 1, ve.y);
            atomicAdd(o + D_FT + qq * 4 + 2, ve.z);
            atomicAdd(o + D_FT + qq * 4 + 3, ve.w);
        }
    }
}

// ---- fallback (R1 atomic path) if ws too small ----
__global__ void scatter_ft_kernel(const float* __restrict__ emb, const float* __restrict__ w,
                                  const int* __restrict__ src_idx, const int* __restrict__ dst_idx,
                                  float* __restrict__ out, int n_items) {
    int idx = blockIdx.x * blockDim.x + threadIdx.x;
    if (idx >= n_items) return;
    int e = idx >> 5, q = idx & 31;
    int s = src_idx[e], d = dst_idx[e];
    const float4 v  = *reinterpret_cast<const float4*>(emb + (size_t)s * D_FT + q * 4);
    const float4 wv = *reinterpret_cast<const float4*>(w + q * 4);
    float* o = out + (size_t)d * D_OUT + q * 4;
    atomicAdd(o + 0, v.x * wv.x); atomicAdd(o + 1, v.y * wv.y);
    atomicAdd(o + 2, v.z * wv.z); atomicAdd(o + 3, v.w * wv.w);
}
__global__ void scatter_e_kernel(const float* __restrict__ e_feat, const int* __restrict__ dst_idx,
                                 float* __restrict__ out, int n_items) {
    int idx = blockIdx.x * blockDim.x + threadIdx.x;
    if (idx >= n_items) return;
    int e = idx >> 3, q = idx & 7;
    int d = dst_idx[e];
    const float4 v = *reinterpret_cast<const float4*>(e_feat + (size_t)e * D_E + q * 4);
    float* o = out + (size_t)d * D_OUT + D_FT + q * 4;
    atomicAdd(o + 0, v.x); atomicAdd(o + 1, v.y);
    atomicAdd(o + 2, v.z); atomicAdd(o + 3, v.w);
}

extern "C" void kernel_launch(void* const* d_in, const int* in_sizes, int n_in,
                              void* d_out, int out_size, void* d_ws, size_t ws_size,
                              hipStream_t stream) {
    const float* emb    = (const float*)d_in[0];   // [N, 128]
    const float* e_feat = (const float*)d_in[1];   // [E, 32]
    const float* w      = (const float*)d_in[2];   // [1, 128]
    const int*   src    = (const int*)d_in[3];     // [E]
    const int*   dst    = (const int*)d_in[4];     // [E]
    float* out = (float*)d_out;                    // [N, 160]

    const int E = in_sizes[3];
    const int N = out_size / D_OUT;

    // ws layout: cursor[N] | ovf_cnt[1] | pad[1] | bucket[N*CAP] int2 | ovf[E]
    size_t ints_head = (size_t)N + 2;
    size_t need = ints_head * 4 + (size_t)N * CAP * 8 + (size_t)E * 4;

    if (ws_size >= need) {
        int*  cursor  = (int*)d_ws;
        int*  ovf_cnt = cursor + N;
        int2* bucket  = (int2*)(cursor + ints_head);
        int*  ovf     = (int*)(bucket + (size_t)N * CAP);

        hipMemsetAsync(cursor, 0, ints_head * sizeof(int), stream);
        place_bucket_kernel<<<(E + 255) / 256, 256, 0, stream>>>(
            src, dst, cursor, bucket, ovf, ovf_cnt, E);
        gather_bucket_kernel<<<((size_t)N * 32 + 255) / 256, 256, 0, stream>>>(
            emb, e_feat, w, cursor, bucket, out, N);
        ovf_scatter_kernel<<<128, 256, 0, stream>>>(
            emb, e_feat, w, src, dst, ovf, ovf_cnt, out);
    } else {
        hipMemsetAsync(d_out, 0, (size_t)out_size * sizeof(float), stream);
        int items_ft = E * 32, items_e = E * 8;
        scatter_ft_kernel<<<(items_ft + 255) / 256, 256, 0, stream>>>(emb, w, src, dst, out, items_ft);
        scatter_e_kernel<<<(items_e + 255) / 256, 256, 0, stream>>>(e_feat, dst, out, items_e);
    }
}